// Round 4
// baseline (264.141 us; speedup 1.0000x reference)
//
#include <hip/hip_runtime.h>
#include <hip/hip_bf16.h>
#include <hip/hip_fp16.h>
#include <math.h>

// Problem constants
#define BSZ 8
#define LSEQ 4096
#define HDIM 512
#define PDIM 256
#define MROWS (BSZ * LSEQ)        // 32768
#define NDIM 512                  // 2*PDIM
#define CHUNK 64
#define NCHUNK (LSEQ / CHUNK)     // 64

typedef __attribute__((ext_vector_type(8))) short bf16x8;
typedef __attribute__((ext_vector_type(4))) float f32x4;

// ---------------------------------------------------------------------------
// x (fp32) -> xb (bf16)
// ---------------------------------------------------------------------------
__global__ __launch_bounds__(256) void convert_x(const float* __restrict__ x,
                                                 __hip_bfloat16* __restrict__ xb,
                                                 int n4) {
    int i = blockIdx.x * blockDim.x + threadIdx.x;
    if (i >= n4) return;
    float4 v = ((const float4*)x)[i];
    union { ushort4 u; __hip_bfloat16 h[4]; } o;
    o.h[0] = __float2bfloat16(v.x);
    o.h[1] = __float2bfloat16(v.y);
    o.h[2] = __float2bfloat16(v.z);
    o.h[3] = __float2bfloat16(v.w);
    ((ushort4*)xb)[i] = o.u;
}

// ---------------------------------------------------------------------------
// W1T (bf16, N x K = 512 x 512): row 2p -> Re(B_bar[p][:]), row 2p+1 -> Im.
// Double-precision transcendentals to match numpy ref. Emits Lambda_bar f32.
// ---------------------------------------------------------------------------
__global__ void precompute_w1(const float* __restrict__ Lre,
                              const float* __restrict__ Lim,
                              const float* __restrict__ logstep,
                              const float* __restrict__ Bmat,  // (P,H,2)
                              __hip_bfloat16* __restrict__ W1T,
                              float* __restrict__ a_re,
                              float* __restrict__ a_im) {
    int idx = blockIdx.x * blockDim.x + threadIdx.x;  // p*H + h
    if (idx >= PDIM * HDIM) return;
    int p = idx / HDIM, h = idx % HDIM;
    double step = exp((double)logstep[p]);
    double dlr = (double)Lre[p], dli = (double)Lim[p];
    double mag = exp(dlr * step);
    double ar = mag * cos(dli * step);
    double ai = mag * sin(dli * step);
    double den = dlr * dlr + dli * dli;
    double nr = ar - 1.0, ni = ai;
    double fr = (nr * dlr + ni * dli) / den;
    double fi = (ni * dlr - nr * dli) / den;
    double br = (double)Bmat[(size_t)(p * HDIM + h) * 2 + 0];
    double bi = (double)Bmat[(size_t)(p * HDIM + h) * 2 + 1];
    W1T[(size_t)(2 * p) * HDIM + h]     = __float2bfloat16((float)(fr * br - fi * bi));
    W1T[(size_t)(2 * p + 1) * HDIM + h] = __float2bfloat16((float)(fr * bi + fi * br));
    if (h == 0) { a_re[p] = (float)ar; a_im[p] = (float)ai; }
}

// W2T (bf16): W2T[h][2p] = 2*C_re[h][p]; [h][2p+1] = -2*C_im[h][p]
__global__ void precompute_w2(const float* __restrict__ Cmat,  // (H,P,2)
                              __hip_bfloat16* __restrict__ W2T) {
    int idx = blockIdx.x * blockDim.x + threadIdx.x;  // h*P + p
    if (idx >= HDIM * PDIM) return;
    int h = idx / PDIM, p = idx % PDIM;
    float cr = Cmat[(size_t)(h * PDIM + p) * 2 + 0];
    float ci = Cmat[(size_t)(h * PDIM + p) * 2 + 1];
    W2T[(size_t)h * NDIM + 2 * p]     = __float2bfloat16(2.0f * cr);
    W2T[(size_t)h * NDIM + 2 * p + 1] = __float2bfloat16(-2.0f * ci);
}

// ---------------------------------------------------------------------------
// bf16 MFMA GEMM: C(MxN, OT) = A(MxK,bf16) @ BT(NxK,bf16)^T [+ D*xskip]
// 64x64 tile, BK=32, 256 threads = 4 waves (2x2 of 32x32), each wave 2x2
// frags of 16x16x32.  Grid 4096 blocks -> 16/CU queue depth (latency hiding).
// ---------------------------------------------------------------------------
template <typename OT, bool SKIP>
__global__ __launch_bounds__(256) void gemm_bt(
    const __hip_bfloat16* __restrict__ A,   // M x K
    const __hip_bfloat16* __restrict__ BT,  // N x K
    OT* __restrict__ C,                     // M x N
    const float* __restrict__ Dvec,
    const __hip_bfloat16* __restrict__ Xskip,
    int M, int N, int K) {
    __shared__ __hip_bfloat16 smA[64 * 32];    // 4 KB
    __shared__ __hip_bfloat16 smB[64 * 32];    // 4 KB

    const int tid = threadIdx.x;
    const int lane = tid & 63;
    const int wave = tid >> 6;            // 0..3
    const int row0 = blockIdx.y * 64;
    const int col0 = blockIdx.x * 64;
    const int wm = (wave >> 1) * 32;
    const int wn = (wave & 1) * 32;

    const int sr = lane >> 2;             // 0..15
    const int sk = (lane & 3) * 8;
    const int quad = lane >> 4;           // 0..3
    const int l15 = lane & 15;

    f32x4 acc[2][2] = {};

    for (int k0 = 0; k0 < K; k0 += 32) {
        const int chunk = wave * 16;      // wave-uniform row group
        const __hip_bfloat16* gA = A + (size_t)(row0 + chunk + sr) * K + k0 + sk;
        const __hip_bfloat16* gB = BT + (size_t)(col0 + chunk + sr) * K + k0 + sk;
        __builtin_amdgcn_global_load_lds(
            (const __attribute__((address_space(1))) void*)gA,
            (__attribute__((address_space(3))) void*)&smA[chunk * 32], 16, 0, 0);
        __builtin_amdgcn_global_load_lds(
            (const __attribute__((address_space(1))) void*)gB,
            (__attribute__((address_space(3))) void*)&smB[chunk * 32], 16, 0, 0);
        __syncthreads();

        bf16x8 af[2], bfr[2];
#pragma unroll
        for (int i = 0; i < 2; ++i) {
            af[i]  = *(const bf16x8*)&smA[(wm + i * 16 + l15) * 32 + quad * 8];
            bfr[i] = *(const bf16x8*)&smB[(wn + i * 16 + l15) * 32 + quad * 8];
        }
#pragma unroll
        for (int i = 0; i < 2; ++i)
#pragma unroll
            for (int j = 0; j < 2; ++j)
                acc[i][j] = __builtin_amdgcn_mfma_f32_16x16x32_bf16(
                    af[i], bfr[j], acc[i][j], 0, 0, 0);
        __syncthreads();
    }

    // Epilogue: D row = quad*4 + r, col = l15 (m89/m91-verified)
#pragma unroll
    for (int i = 0; i < 2; ++i) {
        const int mbase = row0 + wm + i * 16 + quad * 4;
#pragma unroll
        for (int j = 0; j < 2; ++j) {
            const int col = col0 + wn + j * 16 + l15;
            const float dv = SKIP ? Dvec[col] : 0.0f;
#pragma unroll
            for (int r = 0; r < 4; ++r) {
                const size_t m = (size_t)(mbase + r);
                float v = acc[i][j][r];
                if (SKIP) v += dv * __bfloat162float(Xskip[m * N + col]);
                if constexpr (sizeof(OT) == 2) {
                    C[m * N + col] = OT(v);
                } else {
                    C[m * N + col] = v;
                }
            }
        }
    }
}

// ---------------------------------------------------------------------------
// Scan pass A: 128 blocks x 256 threads. Block = (b, 4 chunks); 64-lane group
// g handles chunk cq*4+g; each lane owns 4 complex channels (16 B loads, 4
// independent FMA chains). Bu fp16 interleaved [m][2p]=re,[2p+1]=im.
// ---------------------------------------------------------------------------
__global__ __launch_bounds__(256) void scan_chunks(const __half2* __restrict__ Bu2,
                                                   const float* __restrict__ a_re,
                                                   const float* __restrict__ a_im,
                                                   float2* __restrict__ S) {
    const int b = blockIdx.x >> 4;             // /16
    const int cq = blockIdx.x & 15;
    const int g = threadIdx.x >> 6;
    const int c = cq * 4 + g;
    const int pb = (threadIdx.x & 63) * 4;     // 4 consecutive p
    float4 arv = *(const float4*)&a_re[pb];
    float4 aiv = *(const float4*)&a_im[pb];
    const float ar[4] = {arv.x, arv.y, arv.z, arv.w};
    const float ai[4] = {aiv.x, aiv.y, aiv.z, aiv.w};
    float sr[4] = {}, si[4] = {};
    const size_t m0 = (size_t)b * LSEQ + (size_t)c * CHUNK;
    for (int j = 0; j < CHUNK; ++j) {
        union { float4 f; __half2 h[4]; } u;
        u.f = *(const float4*)&Bu2[(m0 + j) * PDIM + pb];
#pragma unroll
        for (int k = 0; k < 4; ++k) {
            float2 v = __half22float2(u.h[k]);
            float nsr = ar[k] * sr[k] - ai[k] * si[k] + v.x;
            float nsi = ar[k] * si[k] + ai[k] * sr[k] + v.y;
            sr[k] = nsr; si[k] = nsi;
        }
    }
    float2* sp = &S[(size_t)(b * NCHUNK + c) * PDIM + pb];
#pragma unroll
    for (int k = 0; k < 4; ++k) sp[k] = make_float2(sr[k], si[k]);
}

// ---------------------------------------------------------------------------
// Scan pass B: 8 blocks x 256 threads, thread = (b, p). Strip-mined: 8
// independent S-loads in flight, then 8 scan steps -> ~8 latencies total.
// ---------------------------------------------------------------------------
__global__ __launch_bounds__(256) void scan_carry(const float2* __restrict__ S,
                                                  const float* __restrict__ a_re,
                                                  const float* __restrict__ a_im,
                                                  float2* __restrict__ carry) {
    const int b = blockIdx.x;
    const int p = threadIdx.x;
    double ar = (double)a_re[p], ai = (double)a_im[p];
#pragma unroll
    for (int i = 0; i < 6; ++i) {  // a^64 via squaring
        double nr = ar * ar - ai * ai;
        double ni = 2.0 * ar * ai;
        ar = nr; ai = ni;
    }
    const float alr = (float)ar, ali = (float)ai;
    float cr = 0.0f, ci = 0.0f;
    for (int cg = 0; cg < NCHUNK / 8; ++cg) {
        float2 sv[8];
#pragma unroll
        for (int t = 0; t < 8; ++t)
            sv[t] = S[(size_t)(b * NCHUNK + cg * 8 + t) * PDIM + p];
#pragma unroll
        for (int t = 0; t < 8; ++t) {
            carry[(size_t)(b * NCHUNK + cg * 8 + t) * PDIM + p] = make_float2(cr, ci);
            float ncr = alr * cr - ali * ci + sv[t].x;
            float nci = alr * ci + ali * cr + sv[t].y;
            cr = ncr; ci = nci;
        }
    }
}

// ---------------------------------------------------------------------------
// Scan pass C: same decomposition as pass A; seeds from carry, writes xs as
// bf16 interleaved (16 B stores).
// ---------------------------------------------------------------------------
__global__ __launch_bounds__(256) void scan_apply(const __half2* __restrict__ Bu2,
                                                  const float* __restrict__ a_re,
                                                  const float* __restrict__ a_im,
                                                  const float2* __restrict__ carry,
                                                  ushort2* __restrict__ xsb2) {
    const int b = blockIdx.x >> 4;
    const int cq = blockIdx.x & 15;
    const int g = threadIdx.x >> 6;
    const int c = cq * 4 + g;
    const int pb = (threadIdx.x & 63) * 4;
    float4 arv = *(const float4*)&a_re[pb];
    float4 aiv = *(const float4*)&a_im[pb];
    const float ar[4] = {arv.x, arv.y, arv.z, arv.w};
    const float ai[4] = {aiv.x, aiv.y, aiv.z, aiv.w};
    float sr[4], si[4];
    const float2* cp = &carry[(size_t)(b * NCHUNK + c) * PDIM + pb];
#pragma unroll
    for (int k = 0; k < 4; ++k) { float2 c0 = cp[k]; sr[k] = c0.x; si[k] = c0.y; }
    const size_t m0 = (size_t)b * LSEQ + (size_t)c * CHUNK;
    for (int j = 0; j < CHUNK; ++j) {
        const size_t idx = (m0 + j) * PDIM + pb;
        union { float4 f; __half2 h[4]; } u;
        u.f = *(const float4*)&Bu2[idx];
        union { ushort4 o4[2]; __hip_bfloat16 hb[8]; } o;
#pragma unroll
        for (int k = 0; k < 4; ++k) {
            float2 v = __half22float2(u.h[k]);
            float nsr = ar[k] * sr[k] - ai[k] * si[k] + v.x;
            float nsi = ar[k] * si[k] + ai[k] * sr[k] + v.y;
            sr[k] = nsr; si[k] = nsi;
            o.hb[2 * k]     = __float2bfloat16(nsr);
            o.hb[2 * k + 1] = __float2bfloat16(nsi);
        }
        *(float4*)&xsb2[idx] = *(float4*)&o.o4[0];
    }
}

// ---------------------------------------------------------------------------
extern "C" void kernel_launch(void* const* d_in, const int* in_sizes, int n_in,
                              void* d_out, int out_size, void* d_ws, size_t ws_size,
                              hipStream_t stream) {
    const float* x       = (const float*)d_in[0];
    const float* Lre     = (const float*)d_in[1];
    const float* Lim     = (const float*)d_in[2];
    const float* Bmat    = (const float*)d_in[3];
    const float* Cmat    = (const float*)d_in[4];
    const float* Dvec    = (const float*)d_in[5];
    const float* logstep = (const float*)d_in[6];
    float* out = (float*)d_out;

    char* ws = (char*)d_ws;
    const size_t MB = 1u << 20;
    __hip_bfloat16* xb  = (__hip_bfloat16*)(ws + 0);         // 32 MB
    __hip_bfloat16* xsb = (__hip_bfloat16*)(ws + 32 * MB);   // 32 MB
    __half* Bu          = (__half*)(ws + 64 * MB);           // 32 MB
    __hip_bfloat16* W1T = (__hip_bfloat16*)(ws + 96 * MB);   // 0.5 MB
    __hip_bfloat16* W2T = (__hip_bfloat16*)(ws + 96 * MB + 512 * 1024);
    float*  a_re  = (float*)(ws + 97 * MB);
    float*  a_im  = (float*)(ws + 97 * MB + 4096);
    float2* S     = (float2*)(ws + 98 * MB);                 // 1 MB
    float2* carry = (float2*)(ws + 99 * MB);                 // 1 MB

    // 1. Conversions / precompute
    convert_x<<<(MROWS * HDIM / 4 + 255) / 256, 256, 0, stream>>>(
        x, xb, MROWS * HDIM / 4);
    precompute_w1<<<(PDIM * HDIM + 255) / 256, 256, 0, stream>>>(
        Lre, Lim, logstep, Bmat, W1T, a_re, a_im);
    precompute_w2<<<(HDIM * PDIM + 255) / 256, 256, 0, stream>>>(Cmat, W2T);

    // 2. GEMM1: Bu(fp16) = xb @ W1T^T
    dim3 ggrid1(NDIM / 64, MROWS / 64);  // (8, 512) = 4096 blocks
    gemm_bt<__half, false><<<ggrid1, 256, 0, stream>>>(
        xb, W1T, Bu, nullptr, nullptr, MROWS, NDIM, HDIM);

    // 3. Scan (3-pass chunked), emits xs as bf16
    scan_chunks<<<BSZ * NCHUNK / 4, 256, 0, stream>>>(
        (const __half2*)Bu, a_re, a_im, S);
    scan_carry<<<BSZ, 256, 0, stream>>>(S, a_re, a_im, carry);
    scan_apply<<<BSZ * NCHUNK / 4, 256, 0, stream>>>(
        (const __half2*)Bu, a_re, a_im, carry, (ushort2*)xsb);

    // 4. GEMM2: out = xsb @ W2T^T + D*xb
    dim3 ggrid2(HDIM / 64, MROWS / 64);  // (8, 512)
    gemm_bt<float, true><<<ggrid2, 256, 0, stream>>>(
        xsb, W2T, out, Dvec, xb, MROWS, HDIM, NDIM);
}

// Round 5
// 243.699 us; speedup vs baseline: 1.0839x; 1.0839x over previous
//
#include <hip/hip_runtime.h>
#include <hip/hip_bf16.h>
#include <hip/hip_fp16.h>
#include <math.h>

// Problem constants
#define BSZ 8
#define LSEQ 4096
#define HDIM 512
#define PDIM 256
#define MROWS (BSZ * LSEQ)        // 32768
#define NDIM 512                  // 2*PDIM
#define CHUNK 64
#define NCHUNK (LSEQ / CHUNK)     // 64

typedef __attribute__((ext_vector_type(8))) short bf16x8;
typedef __attribute__((ext_vector_type(4))) float f32x4;

// ---------------------------------------------------------------------------
// W1T (bf16, N x K = 512 x 512): row 2p -> Re(B_bar[p][:]), row 2p+1 -> Im.
// Double-precision transcendentals to match numpy ref. Emits Lambda_bar f32.
// ---------------------------------------------------------------------------
__global__ void precompute_w1(const float* __restrict__ Lre,
                              const float* __restrict__ Lim,
                              const float* __restrict__ logstep,
                              const float* __restrict__ Bmat,  // (P,H,2)
                              __hip_bfloat16* __restrict__ W1T,
                              float* __restrict__ a_re,
                              float* __restrict__ a_im) {
    int idx = blockIdx.x * blockDim.x + threadIdx.x;  // p*H + h
    if (idx >= PDIM * HDIM) return;
    int p = idx / HDIM, h = idx % HDIM;
    double step = exp((double)logstep[p]);
    double dlr = (double)Lre[p], dli = (double)Lim[p];
    double mag = exp(dlr * step);
    double ar = mag * cos(dli * step);
    double ai = mag * sin(dli * step);
    double den = dlr * dlr + dli * dli;
    double nr = ar - 1.0, ni = ai;
    double fr = (nr * dlr + ni * dli) / den;
    double fi = (ni * dlr - nr * dli) / den;
    double br = (double)Bmat[(size_t)(p * HDIM + h) * 2 + 0];
    double bi = (double)Bmat[(size_t)(p * HDIM + h) * 2 + 1];
    W1T[(size_t)(2 * p) * HDIM + h]     = __float2bfloat16((float)(fr * br - fi * bi));
    W1T[(size_t)(2 * p + 1) * HDIM + h] = __float2bfloat16((float)(fr * bi + fi * br));
    if (h == 0) { a_re[p] = (float)ar; a_im[p] = (float)ai; }
}

// W2T (bf16): W2T[h][2p] = 2*C_re[h][p]; [h][2p+1] = -2*C_im[h][p]
__global__ void precompute_w2(const float* __restrict__ Cmat,  // (H,P,2)
                              __hip_bfloat16* __restrict__ W2T) {
    int idx = blockIdx.x * blockDim.x + threadIdx.x;  // h*P + p
    if (idx >= HDIM * PDIM) return;
    int h = idx / PDIM, p = idx % PDIM;
    float cr = Cmat[(size_t)(h * PDIM + p) * 2 + 0];
    float ci = Cmat[(size_t)(h * PDIM + p) * 2 + 1];
    W2T[(size_t)h * NDIM + 2 * p]     = __float2bfloat16(2.0f * cr);
    W2T[(size_t)h * NDIM + 2 * p + 1] = __float2bfloat16(-2.0f * ci);
}

// apow[j][p] = a_p^(j+1), j=0..63 (fp32 complex). 1 block x 256 threads.
__global__ void precompute_pow(const float* __restrict__ a_re,
                               const float* __restrict__ a_im,
                               float2* __restrict__ apow) {
    const int p = threadIdx.x;
    const float ar = a_re[p], ai = a_im[p];
    float cr = ar, ci = ai;
    for (int j = 0; j < CHUNK; ++j) {
        apow[j * PDIM + p] = make_float2(cr, ci);
        float nr = cr * ar - ci * ai;
        float ni = cr * ai + ci * ar;
        cr = nr; ci = ni;
    }
}

// ---------------------------------------------------------------------------
// Fused GEMM1 + local scan.  Tile 64(time) x 128(n), BK=32, 256 threads =
// 4 waves (2x2), each wave 2x4 frags of 16x16x32.  A = x fp32 converted to
// bf16 in-register during staging.  M-tile == one time chunk, so after the
// K-loop the block owns Bu[64][128] in accumulators: dump to LDS, wave 0 does
// the per-channel serial scan (fp32), writes local-scan result (fp16) +
// chunk-end state S.
// ---------------------------------------------------------------------------
__global__ __launch_bounds__(256) void gemm1_scan(
    const float* __restrict__ x,            // M x 512 fp32
    const __hip_bfloat16* __restrict__ BT,  // 512 x 512 bf16 (W1T)
    const float* __restrict__ a_re,
    const float* __restrict__ a_im,
    __half2* __restrict__ local2,           // M x 256 half2 (local scan out)
    float2* __restrict__ S) {               // (b*NCHUNK+c) x 256
    __shared__ __hip_bfloat16 smA[64 * 32];    // 4 KB
    __shared__ __hip_bfloat16 smB[128 * 32];   // 8 KB
    __shared__ float stile[64 * 132];          // 33.8 KB (stride 132: 2-way only)

    const int tid = threadIdx.x;
    const int lane = tid & 63;
    const int wave = tid >> 6;
    const int row0 = blockIdx.y * 64;          // = (b*NCHUNK+c)*64
    const int col0 = blockIdx.x * 128;
    const int wm = (wave >> 1) * 32;
    const int wn = (wave & 1) * 64;

    const int sr = lane >> 2;              // 0..15
    const int sk = (lane & 3) * 8;
    const int quad = lane >> 4;
    const int l15 = lane & 15;

    f32x4 acc[2][4] = {};

    for (int k0 = 0; k0 < 512; k0 += 32) {
        {   // A staging: load fp32 x, convert to bf16, ds_write_b128
            const int arow = wave * 16 + sr;
            const float* gx = &x[(size_t)(row0 + arow) * 512 + k0 + sk];
            float4 v0 = *(const float4*)gx;
            float4 v1 = *(const float4*)(gx + 4);
            union { bf16x8 v; __hip_bfloat16 h[8]; } o;
            o.h[0] = __float2bfloat16(v0.x); o.h[1] = __float2bfloat16(v0.y);
            o.h[2] = __float2bfloat16(v0.z); o.h[3] = __float2bfloat16(v0.w);
            o.h[4] = __float2bfloat16(v1.x); o.h[5] = __float2bfloat16(v1.y);
            o.h[6] = __float2bfloat16(v1.z); o.h[7] = __float2bfloat16(v1.w);
            *(bf16x8*)&smA[arow * 32 + sk] = o.v;
        }
#pragma unroll
        for (int q = 0; q < 2; ++q) {      // B staging: 128 rows async
            const int chunk = wave * 32 + q * 16;
            const __hip_bfloat16* gB = BT + (size_t)(col0 + chunk + sr) * 512 + k0 + sk;
            __builtin_amdgcn_global_load_lds(
                (const __attribute__((address_space(1))) void*)gB,
                (__attribute__((address_space(3))) void*)&smB[chunk * 32], 16, 0, 0);
        }
        __syncthreads();

        bf16x8 af[2], bfr[4];
#pragma unroll
        for (int i = 0; i < 2; ++i)
            af[i] = *(const bf16x8*)&smA[(wm + i * 16 + l15) * 32 + quad * 8];
#pragma unroll
        for (int j = 0; j < 4; ++j)
            bfr[j] = *(const bf16x8*)&smB[(wn + j * 16 + l15) * 32 + quad * 8];
#pragma unroll
        for (int i = 0; i < 2; ++i)
#pragma unroll
            for (int j = 0; j < 4; ++j)
                acc[i][j] = __builtin_amdgcn_mfma_f32_16x16x32_bf16(
                    af[i], bfr[j], acc[i][j], 0, 0, 0);
        __syncthreads();
    }

    // Dump accumulators to stile[row][col] (row = time within chunk, col = n)
#pragma unroll
    for (int i = 0; i < 2; ++i) {
        const int rbase = wm + i * 16 + quad * 4;
#pragma unroll
        for (int j = 0; j < 4; ++j) {
            const int col = wn + j * 16 + l15;
#pragma unroll
            for (int r = 0; r < 4; ++r)
                stile[(rbase + r) * 132 + col] = acc[i][j][r];
        }
    }
    __syncthreads();

    // Serial local scan: thread t (wave 0) owns channel pair (2t, 2t+1)
    if (tid < 64) {
        const int pg = blockIdx.x * 64 + tid;   // global p
        const float ar = a_re[pg], ai = a_im[pg];
        float sr_ = 0.0f, si_ = 0.0f;
        const size_t mbase = (size_t)row0 * PDIM + pg;
        for (int j = 0; j < CHUNK; ++j) {
            float2 u = *(const float2*)&stile[j * 132 + 2 * tid];
            float nsr = ar * sr_ - ai * si_ + u.x;
            float nsi = ar * si_ + ai * sr_ + u.y;
            sr_ = nsr; si_ = nsi;
            local2[mbase + (size_t)j * PDIM] = __float22half2_rn(make_float2(nsr, nsi));
        }
        S[(size_t)blockIdx.y * PDIM + pg] = make_float2(sr_, si_);
    }
}

// ---------------------------------------------------------------------------
// Scan carry: 8 blocks x 256 threads, thread = (b, p). Strip-mined loads.
// ---------------------------------------------------------------------------
__global__ __launch_bounds__(256) void scan_carry(const float2* __restrict__ S,
                                                  const float* __restrict__ a_re,
                                                  const float* __restrict__ a_im,
                                                  float2* __restrict__ carry) {
    const int b = blockIdx.x;
    const int p = threadIdx.x;
    double ar = (double)a_re[p], ai = (double)a_im[p];
#pragma unroll
    for (int i = 0; i < 6; ++i) {  // a^64 via squaring
        double nr = ar * ar - ai * ai;
        double ni = 2.0 * ar * ai;
        ar = nr; ai = ni;
    }
    const float alr = (float)ar, ali = (float)ai;
    float cr = 0.0f, ci = 0.0f;
    for (int cg = 0; cg < NCHUNK / 8; ++cg) {
        float2 sv[8];
#pragma unroll
        for (int t = 0; t < 8; ++t)
            sv[t] = S[(size_t)(b * NCHUNK + cg * 8 + t) * PDIM + p];
#pragma unroll
        for (int t = 0; t < 8; ++t) {
            carry[(size_t)(b * NCHUNK + cg * 8 + t) * PDIM + p] = make_float2(cr, ci);
            float ncr = alr * cr - ali * ci + sv[t].x;
            float nci = alr * ci + ali * cr + sv[t].y;
            cr = ncr; ci = nci;
        }
    }
}

// ---------------------------------------------------------------------------
// Apply: xs[m] = local[m] + a^(j+1) * carry[b,c]  (j = m % 64), elementwise.
// Grid 512 blocks = one per (b, chunk); 256 threads = 4 rows x 64 p-quads.
// Writes xs as bf16 interleaved.
// ---------------------------------------------------------------------------
__global__ __launch_bounds__(256) void apply_carry(
    const __half2* __restrict__ local2,   // M x 256
    const float2* __restrict__ apow,      // 64 x 256
    const float2* __restrict__ carry,     // (b*NCHUNK+c) x 256
    ushort2* __restrict__ xsb2) {         // M x 256 (bf16 pairs)
    const int bc = blockIdx.x;
    const int slot = threadIdx.x & 63;    // p-quad: p0 = slot*4
    const int rgrp = threadIdx.x >> 6;    // 0..3

    float2 cv[4];
    {
        float4 c01 = *(const float4*)&carry[(size_t)bc * PDIM + slot * 4];
        float4 c23 = *(const float4*)&carry[(size_t)bc * PDIM + slot * 4 + 2];
        cv[0] = make_float2(c01.x, c01.y); cv[1] = make_float2(c01.z, c01.w);
        cv[2] = make_float2(c23.x, c23.y); cv[3] = make_float2(c23.z, c23.w);
    }

    for (int jg = 0; jg < CHUNK / 4; ++jg) {
        const int j = jg * 4 + rgrp;
        const size_t m = (size_t)bc * CHUNK + j;
        union { float4 f; __half2 h[4]; } u;
        u.f = ((const float4*)local2)[m * 64 + slot];
        float4 p01 = *(const float4*)&apow[j * PDIM + slot * 4];
        float4 p23 = *(const float4*)&apow[j * PDIM + slot * 4 + 2];
        const float2 pw[4] = {make_float2(p01.x, p01.y), make_float2(p01.z, p01.w),
                              make_float2(p23.x, p23.y), make_float2(p23.z, p23.w)};
        union { ushort4 o4[2]; __hip_bfloat16 hb[8]; } o;
#pragma unroll
        for (int k = 0; k < 4; ++k) {
            float2 v = __half22float2(u.h[k]);
            float re = v.x + pw[k].x * cv[k].x - pw[k].y * cv[k].y;
            float im = v.y + pw[k].x * cv[k].y + pw[k].y * cv[k].x;
            o.hb[2 * k]     = __float2bfloat16(re);
            o.hb[2 * k + 1] = __float2bfloat16(im);
        }
        *(float4*)&xsb2[m * PDIM + slot * 4] = *(float4*)&o.o4[0];
    }
}

// ---------------------------------------------------------------------------
// GEMM2: out(f32) = xs(bf16) @ W2T^T + D * x(fp32).  64x128 tile, BK=32,
// round-3 structure (best measured shape).
// ---------------------------------------------------------------------------
__global__ __launch_bounds__(256) void gemm2(
    const __hip_bfloat16* __restrict__ A,   // M x 512 (xs bf16)
    const __hip_bfloat16* __restrict__ BT,  // 512 x 512 (W2T)
    float* __restrict__ C,                  // M x 512
    const float* __restrict__ Dvec,
    const float* __restrict__ Xskip) {      // fp32 x
    __shared__ __hip_bfloat16 smA[64 * 32];
    __shared__ __hip_bfloat16 smB[128 * 32];

    const int tid = threadIdx.x;
    const int lane = tid & 63;
    const int wave = tid >> 6;
    const int row0 = blockIdx.y * 64;
    const int col0 = blockIdx.x * 128;
    const int wm = (wave >> 1) * 32;
    const int wn = (wave & 1) * 64;

    const int sr = lane >> 2;
    const int sk = (lane & 3) * 8;
    const int quad = lane >> 4;
    const int l15 = lane & 15;

    f32x4 acc[2][4] = {};

    for (int k0 = 0; k0 < 512; k0 += 32) {
        {
            const int chunk = wave * 16;
            const __hip_bfloat16* gA = A + (size_t)(row0 + chunk + sr) * 512 + k0 + sk;
            __builtin_amdgcn_global_load_lds(
                (const __attribute__((address_space(1))) void*)gA,
                (__attribute__((address_space(3))) void*)&smA[chunk * 32], 16, 0, 0);
        }
#pragma unroll
        for (int q = 0; q < 2; ++q) {
            const int chunk = wave * 32 + q * 16;
            const __hip_bfloat16* gB = BT + (size_t)(col0 + chunk + sr) * 512 + k0 + sk;
            __builtin_amdgcn_global_load_lds(
                (const __attribute__((address_space(1))) void*)gB,
                (__attribute__((address_space(3))) void*)&smB[chunk * 32], 16, 0, 0);
        }
        __syncthreads();

        bf16x8 af[2], bfr[4];
#pragma unroll
        for (int i = 0; i < 2; ++i)
            af[i] = *(const bf16x8*)&smA[(wm + i * 16 + l15) * 32 + quad * 8];
#pragma unroll
        for (int j = 0; j < 4; ++j)
            bfr[j] = *(const bf16x8*)&smB[(wn + j * 16 + l15) * 32 + quad * 8];
#pragma unroll
        for (int i = 0; i < 2; ++i)
#pragma unroll
            for (int j = 0; j < 4; ++j)
                acc[i][j] = __builtin_amdgcn_mfma_f32_16x16x32_bf16(
                    af[i], bfr[j], acc[i][j], 0, 0, 0);
        __syncthreads();
    }

#pragma unroll
    for (int i = 0; i < 2; ++i) {
        const int mbase = row0 + wm + i * 16 + quad * 4;
#pragma unroll
        for (int j = 0; j < 4; ++j) {
            const int col = col0 + wn + j * 16 + l15;
            const float dv = Dvec[col];
#pragma unroll
            for (int r = 0; r < 4; ++r) {
                const size_t m = (size_t)(mbase + r);
                C[m * 512 + col] = acc[i][j][r] + dv * Xskip[m * 512 + col];
            }
        }
    }
}

// ---------------------------------------------------------------------------
extern "C" void kernel_launch(void* const* d_in, const int* in_sizes, int n_in,
                              void* d_out, int out_size, void* d_ws, size_t ws_size,
                              hipStream_t stream) {
    const float* x       = (const float*)d_in[0];
    const float* Lre     = (const float*)d_in[1];
    const float* Lim     = (const float*)d_in[2];
    const float* Bmat    = (const float*)d_in[3];
    const float* Cmat    = (const float*)d_in[4];
    const float* Dvec    = (const float*)d_in[5];
    const float* logstep = (const float*)d_in[6];
    float* out = (float*)d_out;

    char* ws = (char*)d_ws;
    const size_t MB = 1u << 20;
    __half2* local2     = (__half2*)(ws + 0);                // 32 MB
    ushort2* xsb2       = (ushort2*)(ws + 32 * MB);          // 32 MB
    __hip_bfloat16* W1T = (__hip_bfloat16*)(ws + 64 * MB);   // 0.5 MB
    __hip_bfloat16* W2T = (__hip_bfloat16*)(ws + 64 * MB + 512 * 1024);
    float*  a_re  = (float*)(ws + 65 * MB);
    float*  a_im  = (float*)(ws + 65 * MB + 4096);
    float2* apow  = (float2*)(ws + 66 * MB);                 // 128 KB
    float2* S     = (float2*)(ws + 67 * MB);                 // 1 MB
    float2* carry = (float2*)(ws + 68 * MB);                 // 1 MB

    // 1. Precompute weights, decay, power table
    precompute_w1<<<(PDIM * HDIM + 255) / 256, 256, 0, stream>>>(
        Lre, Lim, logstep, Bmat, W1T, a_re, a_im);
    precompute_w2<<<(HDIM * PDIM + 255) / 256, 256, 0, stream>>>(Cmat, W2T);
    precompute_pow<<<1, 256, 0, stream>>>(a_re, a_im, apow);

    // 2. Fused GEMM1 + local scan
    dim3 g1(NDIM / 128, MROWS / 64);   // (4, 512)
    gemm1_scan<<<g1, 256, 0, stream>>>(x, W1T, a_re, a_im, local2, S);

    // 3. Chunk-carry prefix
    scan_carry<<<BSZ, 256, 0, stream>>>(S, a_re, a_im, carry);

    // 4. Elementwise carry application -> xs (bf16)
    apply_carry<<<BSZ * NCHUNK, 256, 0, stream>>>(local2, apow, carry, xsb2);

    // 5. GEMM2 with fused D*x skip
    dim3 g2(HDIM / 128, MROWS / 64);   // (4, 512)
    gemm2<<<g2, 256, 0, stream>>>((const __hip_bfloat16*)xsb2, W2T, out, Dvec, x);
}